// Round 17
// baseline (404.810 us; speedup 1.0000x reference)
//
#include <hip/hip_runtime.h>
#include <cfloat>

#define NTOK 65536
#define DIM  512
#define KCB  1024
#define TAU  0.12f
#define REF_CAP 4096

typedef unsigned short u16;
typedef __attribute__((ext_vector_type(8))) _Float16 half8;
typedef __attribute__((ext_vector_type(4))) float f32x4;

#define AS1(p) ((const __attribute__((address_space(1))) void*)(p))
#define AS3(p) ((__attribute__((address_space(3))) void*)(p))

// ---------------- ws layout (bytes) ----------------
// 0       : idx       int[NTOK]        262144
// 262144  : esq       f32[KCB]         4096    -> 266240
// 266240  : refCount  int (16B pad)            -> 266256
// 266256  : refList   int[REF_CAP]     16384   -> 282640
// 282640  : n         f32                      -> 282656 (pad)
// 282656  : counts    int[KCB]         4096    -> 286752
// 286752  : cursor    int[KCB]         4096    -> 290848
// 290848  : base      int[KCB]         4096    -> 294944
// 294976  : E_hf      f16[KCB*DIM]     1048576 -> 1343552
// esum f32[KCB*DIM] (2 MB) aliases E_hf.. (dead after score), end 2392128
// toklist int[NTOK] lives in d_out's out2 region (dead until out24_kernel)

__device__ __forceinline__ u16 h2u(_Float16 h) {
    u16 u; __builtin_memcpy(&u, &h, 2); return u;
}

// Fused E prep: wave per code row -> esq (shuffle reduce) + packed f16 Ehf
__global__ __launch_bounds__(256) void eprep_kernel(const float* __restrict__ E,
                                                    float* __restrict__ esq,
                                                    u16* __restrict__ Ehf)
{
    const int lane = threadIdx.x & 63;
    const int wv   = threadIdx.x >> 6;
    const int k    = blockIdx.x * 4 + wv;
    const float* er = E + (size_t)k * DIM + lane * 8;
    const float4 a = *(const float4*)er;
    const float4 b = *(const float4*)(er + 4);
    float s = a.x*a.x + a.y*a.y + a.z*a.z + a.w*a.w
            + b.x*b.x + b.y*b.y + b.z*b.z + b.w*b.w;
    const float v[8] = {a.x, a.y, a.z, a.w, b.x, b.y, b.z, b.w};
    unsigned int* ep = (unsigned int*)Ehf + (size_t)k * 256 + lane * 4;
    #pragma unroll
    for (int j = 0; j < 4; ++j) {
        const _Float16 h0 = (_Float16)v[2*j], h1 = (_Float16)v[2*j+1];
        ep[j] = ((unsigned int)h2u(h1) << 16) | h2u(h0);
    }
    for (int off = 32; off > 0; off >>= 1) s += __shfl_down(s, off, 64);
    if (lane == 0) esq[k] = s;
}

// Convert one f32 to f16 hi + f16 residual, all-static indices (rule #20)
#define CVT(ZH, ZL, J, VAL) { const _Float16 hv_ = (_Float16)(VAL); \
    (ZH)[J] = hv_; (ZL)[J] = (_Float16)((VAL) - (float)hv_); }

#define LOADK(KC, ZH, ZL) { \
    const float4 a_ = *(const float4*)(zr + (KC) * 32); \
    const float4 b_ = *(const float4*)(zr + (KC) * 32 + 4); \
    CVT(ZH, ZL, 0, a_.x) CVT(ZH, ZL, 1, a_.y) \
    CVT(ZH, ZL, 2, a_.z) CVT(ZH, ZL, 3, a_.w) \
    CVT(ZH, ZL, 4, b_.x) CVT(ZH, ZL, 5, b_.y) \
    CVT(ZH, ZL, 6, b_.z) CVT(ZH, ZL, 7, b_.w) }

// Loop-invariant per-lane LDS read offsets (elements) within a 16-row half
#define DSOFF(KC) const int off##KC = lo16 * 512 + \
    (((((KC) << 2) | hi16) ^ lo16) << 3);

// B-frag read: precomputed offset + compile-time half offset (HOFF folds
// into the ds_read offset immediate) -> zero per-chunk addr VALU
#define KSTEP(KC, ZH, ZL, HOFF) { \
    const half8 eh_ = *(const half8*)&ehi_t[off##KC + (HOFF)]; \
    accA = __builtin_amdgcn_mfma_f32_16x16x32_f16((ZH), eh_, accA, 0, 0, 0); \
    accB = __builtin_amdgcn_mfma_f32_16x16x32_f16((ZL), eh_, accB, 0, 0, 0); }

// stage 32-code tile: 8 waves x 4 rows, named induction pointers
#define STAGE { \
    __builtin_amdgcn_global_load_lds(AS1(gp0), AS3(&ehi_t[c0 * 512]), 16, 0, 0); \
    __builtin_amdgcn_global_load_lds(AS1(gp1), AS3(&ehi_t[c1 * 512]), 16, 0, 0); \
    __builtin_amdgcn_global_load_lds(AS1(gp2), AS3(&ehi_t[c2 * 512]), 16, 0, 0); \
    __builtin_amdgcn_global_load_lds(AS1(gp3), AS3(&ehi_t[c3 * 512]), 16, 0, 0); \
    gp0 += 16384; gp1 += 16384; gp2 += 16384; gp3 += 16384; }

// one 16-code half: 16 ds_read + 32 MFMA + top-2 update
#define COMPUTE(HOFF, CODE0) { \
    const int code_ = (CODE0) + lo16; \
    const float ej = esq_lds[code_]; \
    f32x4 accA = {0.f, 0.f, 0.f, 0.f}; \
    f32x4 accB = {0.f, 0.f, 0.f, 0.f}; \
    __builtin_amdgcn_s_setprio(1); \
    KSTEP(0,  zh0,  zl0,  HOFF) KSTEP(1,  zh1,  zl1,  HOFF) \
    KSTEP(2,  zh2,  zl2,  HOFF) KSTEP(3,  zh3,  zl3,  HOFF) \
    KSTEP(4,  zh4,  zl4,  HOFF) KSTEP(5,  zh5,  zl5,  HOFF) \
    KSTEP(6,  zh6,  zl6,  HOFF) KSTEP(7,  zh7,  zl7,  HOFF) \
    KSTEP(8,  zh8,  zl8,  HOFF) KSTEP(9,  zh9,  zl9,  HOFF) \
    KSTEP(10, zh10, zl10, HOFF) KSTEP(11, zh11, zl11, HOFF) \
    KSTEP(12, zh12, zl12, HOFF) KSTEP(13, zh13, zl13, HOFF) \
    KSTEP(14, zh14, zl14, HOFF) KSTEP(15, zh15, zl15, HOFF) \
    __builtin_amdgcn_s_setprio(0); \
    _Pragma("unroll") \
    for (int r = 0; r < 4; ++r) { \
        const float dist = fmaf(-2.0f, accB[r], fmaf(-2.0f, accA[r], ej)); \
        if (dist < d1[r]) { d2[r] = d1[r]; d1[r] = dist; i1[r] = code_; } \
        else              { d2[r] = fminf(d2[r], dist); } \
    } }

// MFMA split-f16 scoring: 128 tokens/block (8 waves x 16 tokens, K=512 in
// named regs); 32 chunks of 32 codes, single-buffer LDS, 2-barrier template.
// Fused hist: epilogue atomicAdds final indices into counts.
__global__ __launch_bounds__(512, 2) void score_kernel(
    const float* __restrict__ z,
    const u16* __restrict__ Ehf,
    const float* __restrict__ esq,
    int* __restrict__ idx_ws, float* __restrict__ idx_out,
    int* __restrict__ refCount, int* __restrict__ refList,
    int* __restrict__ counts)
{
    __shared__ _Float16 ehi_t[32 * 512];   // 32 KB, granule-swizzled rows
    __shared__ float esq_lds[KCB];         // 4 KB

    const int tid  = threadIdx.x;
    const int lane = tid & 63;
    const int wv   = tid >> 6;             // 0..7
    const int lo16 = lane & 15;
    const int hi16 = lane >> 4;
    const int blk  = blockIdx.x;
    const int tokbase = blk * 128 + wv * 16;

    for (int i = tid; i < KCB; i += 512) esq_lds[i] = esq[i];

    // A fragments: 16 tokens x K=512, f16 hi/lo, NAMED registers.
    // A[row][k]: row = lo16, k = kc*32 + hi16*8 + j
    const float* zr = z + (size_t)(tokbase + lo16) * DIM + (hi16 << 3);
    half8 zh0,zh1,zh2,zh3,zh4,zh5,zh6,zh7,zh8,zh9,zh10,zh11,zh12,zh13,zh14,zh15;
    half8 zl0,zl1,zl2,zl3,zl4,zl5,zl6,zl7,zl8,zl9,zl10,zl11,zl12,zl13,zl14,zl15;
    LOADK(0,  zh0,  zl0)  LOADK(1,  zh1,  zl1)  LOADK(2,  zh2,  zl2)
    LOADK(3,  zh3,  zl3)  LOADK(4,  zh4,  zl4)  LOADK(5,  zh5,  zl5)
    LOADK(6,  zh6,  zl6)  LOADK(7,  zh7,  zl7)  LOADK(8,  zh8,  zl8)
    LOADK(9,  zh9,  zl9)  LOADK(10, zh10, zl10) LOADK(11, zh11, zl11)
    LOADK(12, zh12, zl12) LOADK(13, zh13, zl13) LOADK(14, zh14, zl14)
    LOADK(15, zh15, zl15)

    // precomputed LDS read offsets (loop-invariant)
    DSOFF(0)  DSOFF(1)  DSOFF(2)  DSOFF(3)
    DSOFF(4)  DSOFF(5)  DSOFF(6)  DSOFF(7)
    DSOFF(8)  DSOFF(9)  DSOFF(10) DSOFF(11)
    DSOFF(12) DSOFF(13) DSOFF(14) DSOFF(15)

    // staging induction pointers: wave wv stages tile rows wv*4..wv*4+3;
    // per-lane pre-swizzled source so swizzled reads are conflict-free
    const int c0 = (wv << 2), c1 = c0 + 1, c2 = c0 + 2, c3 = c0 + 3;
    const u16* gp0 = Ehf + (size_t)c0 * 512 + ((lane ^ (c0 & 15)) << 3);
    const u16* gp1 = Ehf + (size_t)c1 * 512 + ((lane ^ (c1 & 15)) << 3);
    const u16* gp2 = Ehf + (size_t)c2 * 512 + ((lane ^ (c2 & 15)) << 3);
    const u16* gp3 = Ehf + (size_t)c3 * 512 + ((lane ^ (c3 & 15)) << 3);

    float d1[4], d2[4]; int i1[4];
    #pragma unroll
    for (int r = 0; r < 4; ++r) { d1[r] = FLT_MAX; d2[r] = FLT_MAX; i1[r] = KCB; }

    for (int ch = 0; ch < 32; ++ch) {
        __syncthreads();   // previous chunk's reads done before overwrite
        STAGE
        __syncthreads();   // drains vmcnt: tile ready (compiler-managed)
        COMPUTE(0,    (ch << 5))        // codes [ch*32,      ch*32 + 16)
        COMPUTE(8192, (ch << 5) + 16)   // codes [ch*32 + 16, ch*32 + 32)
    }

    // merge top-2 across the 16 code-lanes (low 4 lane bits)
    #pragma unroll
    for (int off = 1; off < 16; off <<= 1) {
        #pragma unroll
        for (int r = 0; r < 4; ++r) {
            const float od1 = __shfl_xor(d1[r], off, 64);
            const int   oi1 = __shfl_xor(i1[r], off, 64);
            const float od2 = __shfl_xor(d2[r], off, 64);
            float loser;
            if (od1 < d1[r] || (od1 == d1[r] && oi1 < i1[r])) {
                loser = d1[r]; d1[r] = od1; i1[r] = oi1;
            } else {
                loser = od1;
            }
            d2[r] = fminf(fminf(d2[r], od2), loser);
        }
    }
    if (lo16 == 0) {
        #pragma unroll
        for (int r = 0; r < 4; ++r) {
            const int token = tokbase + (hi16 << 2) + r;
            idx_ws[token]  = i1[r];
            idx_out[token] = (float)i1[r];
            atomicAdd(&counts[i1[r]], 1);          // fused histogram
            if (d2[r] - d1[r] < TAU) {
                int slot = atomicAdd(refCount, 1);
                if (slot < REF_CAP) refList[slot] = token;
            }
        }
    }
}

// f64 exact re-scoring of near-tie tokens. 16 groups of 16 lanes per block;
// group owns a code (lane = 32 dims), 2 codes in flight, 4-level reduce.
// Adjusts counts when the index changes (keeps fused histogram exact).
__global__ __launch_bounds__(256) void refine_kernel(
    const float* __restrict__ z, const float* __restrict__ E,
    const int* __restrict__ refCount, const int* __restrict__ refList,
    int* __restrict__ idx_ws, float* __restrict__ idx_out,
    int* __restrict__ counts)
{
    __shared__ double dists[KCB];
    const int tid = threadIdx.x;
    const int grp = tid >> 4;
    const int q   = tid & 15;
    int rc = *refCount; if (rc > REF_CAP) rc = REF_CAP;
    for (int r = blockIdx.x; r < rc; r += gridDim.x) {
        const int token = refList[r];
        double zr[32];
        {
            const float* zp = z + (size_t)token * DIM + q * 32;
            #pragma unroll
            for (int j = 0; j < 8; ++j) {
                const float4 v = *(const float4*)(zp + j * 4);
                zr[j*4+0] = (double)v.x; zr[j*4+1] = (double)v.y;
                zr[j*4+2] = (double)v.z; zr[j*4+3] = (double)v.w;
            }
        }
        for (int c = grp; c < KCB; c += 32) {
            const int c2 = c + 16;
            const float* ep  = E + (size_t)c  * DIM + q * 32;
            const float* ep2 = E + (size_t)c2 * DIM + q * 32;
            double s = 0.0, s2 = 0.0;
            #pragma unroll
            for (int j = 0; j < 8; ++j) {
                const float4 a = *(const float4*)(ep  + j * 4);
                const float4 b = *(const float4*)(ep2 + j * 4);
                double d;
                d = zr[j*4+0] - (double)a.x; s  = fma(d, d, s);
                d = zr[j*4+1] - (double)a.y; s  = fma(d, d, s);
                d = zr[j*4+2] - (double)a.z; s  = fma(d, d, s);
                d = zr[j*4+3] - (double)a.w; s  = fma(d, d, s);
                d = zr[j*4+0] - (double)b.x; s2 = fma(d, d, s2);
                d = zr[j*4+1] - (double)b.y; s2 = fma(d, d, s2);
                d = zr[j*4+2] - (double)b.z; s2 = fma(d, d, s2);
                d = zr[j*4+3] - (double)b.w; s2 = fma(d, d, s2);
            }
            #pragma unroll
            for (int off = 1; off < 16; off <<= 1) {
                s  += __shfl_xor(s,  off, 64);
                s2 += __shfl_xor(s2, off, 64);
            }
            if (q == 0) { dists[c] = s; dists[c2] = s2; }
        }
        __syncthreads();
        if (tid < 64) {
            const int lane = tid;
            double best = dists[lane]; int bi = lane;
            for (int c = lane + 64; c < KCB; c += 64) {
                const double dv = dists[c];
                if (dv < best) { best = dv; bi = c; }   // ascending: keeps lowest idx
            }
            for (int off = 32; off > 0; off >>= 1) {
                const double ob = __shfl_down(best, off, 64);
                const int    oi = __shfl_down(bi, off, 64);
                if (ob < best || (ob == best && oi < bi)) { best = ob; bi = oi; }
            }
            if (lane == 0) {
                const int old = idx_ws[token];
                if (bi != old) {
                    atomicSub(&counts[old], 1);
                    atomicAdd(&counts[bi], 1);
                    idx_ws[token]  = bi;
                    idx_out[token] = (float)bi;
                }
            }
        }
        __syncthreads();
    }
}

// scan (exclusive prefix of counts -> cursor/base) + fused cs_n epilogue
__global__ __launch_bounds__(1024) void scan_kernel(const int* __restrict__ counts,
                                                    int* __restrict__ cursor,
                                                    int* __restrict__ base,
                                                    const float* __restrict__ cs,
                                                    float* __restrict__ out3,
                                                    float* __restrict__ n_ws)
{
    const int tid = threadIdx.x, lane = tid & 63, wv = tid >> 6;
    const int v = counts[tid];
    int s = v;
    #pragma unroll
    for (int off = 1; off < 64; off <<= 1) {
        const int nb = __shfl_up(s, off, 64);
        if (lane >= off) s += nb;
    }
    __shared__ int wsum[16], wbase[16];
    if (lane == 63) wsum[wv] = s;
    __syncthreads();
    if (tid == 0) {
        int r = 0;
        for (int w = 0; w < 16; ++w) { wbase[w] = r; r += wsum[w]; }
    }
    __syncthreads();
    const int excl = wbase[wv] + s - v;
    cursor[tid] = excl;
    base[tid]   = excl;

    // fused cs_n: out3 = EMA(cluster_size), n = sum(out3)
    const float ncs = 0.99f * cs[tid] + 0.01f * (float)v;
    out3[tid] = ncs;
    float fs = ncs;
    for (int off = 32; off > 0; off >>= 1) fs += __shfl_down(fs, off, 64);
    __shared__ float red[16];
    if (lane == 0) red[wv] = fs;
    __syncthreads();
    if (tid == 0) {
        float t = 0.f;
        for (int i = 0; i < 16; ++i) t += red[i];
        n_ws[0] = t;
    }
}

__global__ __launch_bounds__(256) void scatter_kernel(const int* __restrict__ idx,
                                                      int* __restrict__ cursor,
                                                      int* __restrict__ toklist)
{
    const int b0 = blockIdx.x * 1024;
    #pragma unroll
    for (int j = 0; j < 4; ++j) {
        const int t = b0 + j * 256 + threadIdx.x;
        const int k = idx[t];
        const int slot = atomicAdd(&cursor[k], 1);
        toklist[slot] = t;
    }
}

// Uniform-work segment sum: block b owns sorted slots [b*64, b*64+64).
// 128 threads x float4 (thread owns dims 4*tid..4*tid+3); 4-deep row
// prefetch (all static indices) for memory-level parallelism.
#define SSLD(I) *(const float4*)(z + (size_t)toks[I] * DIM + d)
#define SSPROC(I, V) { \
    const int k_ = ks[I]; \
    if (k_ != curk) { \
        atomicAdd(&esum[(size_t)curk * DIM + d],     acc.x); \
        atomicAdd(&esum[(size_t)curk * DIM + d + 1], acc.y); \
        atomicAdd(&esum[(size_t)curk * DIM + d + 2], acc.z); \
        atomicAdd(&esum[(size_t)curk * DIM + d + 3], acc.w); \
        acc.x = 0.f; acc.y = 0.f; acc.z = 0.f; acc.w = 0.f; \
        curk = k_; \
        er = *(const float4*)(E + (size_t)k_ * DIM + d); \
    } \
    *(float4*)(out0 + (size_t)toks[I] * DIM + d) = er; \
    acc.x += (V).x; acc.y += (V).y; acc.z += (V).z; acc.w += (V).w; }

__global__ __launch_bounds__(128) void seg_sum_kernel(
    const float* __restrict__ z, const float* __restrict__ E,
    const int* __restrict__ toklist, const int* __restrict__ idx,
    float* __restrict__ out0, float* __restrict__ esum)
{
    __shared__ int toks[64];
    __shared__ int ks[64];
    const int tid  = threadIdx.x;
    const int seg0 = blockIdx.x * 64;
    if (tid < 64) toks[tid] = toklist[seg0 + tid];
    __syncthreads();
    if (tid < 64) ks[tid] = idx[toks[tid]];
    __syncthreads();

    const int d = tid * 4;
    int curk = ks[0];
    float4 er  = *(const float4*)(E + (size_t)curk * DIM + d);
    float4 acc = {0.f, 0.f, 0.f, 0.f};
    float4 cur0 = SSLD(0), cur1 = SSLD(1), cur2 = SSLD(2), cur3 = SSLD(3);
    for (int i = 0; i < 64; i += 4) {
        float4 nx0, nx1, nx2, nx3;
        if (i < 60) {
            nx0 = SSLD(i + 4); nx1 = SSLD(i + 5);
            nx2 = SSLD(i + 6); nx3 = SSLD(i + 7);
        }
        SSPROC(i,     cur0)
        SSPROC(i + 1, cur1)
        SSPROC(i + 2, cur2)
        SSPROC(i + 3, cur3)
        cur0 = nx0; cur1 = nx1; cur2 = nx2; cur3 = nx3;
    }
    atomicAdd(&esum[(size_t)curk * DIM + d],     acc.x);
    atomicAdd(&esum[(size_t)curk * DIM + d + 1], acc.y);
    atomicAdd(&esum[(size_t)curk * DIM + d + 2], acc.z);
    atomicAdd(&esum[(size_t)curk * DIM + d + 3], acc.w);
}

__global__ __launch_bounds__(256) void out24_kernel(const float* __restrict__ ea,
    const float* __restrict__ esum, const float* __restrict__ out3,
    const float* __restrict__ n_ws, float* __restrict__ out2,
    float* __restrict__ out4)
{
    const size_t i = (size_t)blockIdx.x * 256 + threadIdx.x;
    const int k = (int)(i >> 9);
    const float n = n_ws[0];
    const float smoothed = (out3[k] + 1e-5f) / (n + 0.01024f) * n;
    const float nea = 0.99f * ea[i] + 0.01f * esum[i];
    out4[i] = nea;
    out2[i] = nea / smoothed;
}

extern "C" void kernel_launch(void* const* d_in, const int* in_sizes, int n_in,
                              void* d_out, int out_size, void* d_ws, size_t ws_size,
                              hipStream_t stream)
{
    const float* z  = (const float*)d_in[0];
    const float* E  = (const float*)d_in[1];
    const float* cs = (const float*)d_in[2];
    const float* ea = (const float*)d_in[3];

    float* out0 = (float*)d_out;                       // quantized_st [NTOK*DIM]
    float* out1 = out0 + (size_t)NTOK * DIM;           // indices (as f32) [NTOK]
    float* out2 = out1 + NTOK;                         // new_embedding [KCB*DIM]
    float* out3 = out2 + (size_t)KCB * DIM;            // new_cluster_size [KCB]
    float* out4 = out3 + KCB;                          // new_embed_avg [KCB*DIM]

    char* ws = (char*)d_ws;
    int*   idx_ws  = (int*)ws;
    float* esq     = (float*)(ws + 262144);
    int*   refCnt  = (int*)(ws + 266240);
    int*   refList = (int*)(ws + 266256);
    float* n_ws    = (float*)(ws + 282640);
    int*   counts  = (int*)(ws + 282656);
    int*   cursor  = (int*)(ws + 286752);
    int*   base    = (int*)(ws + 290848);
    u16*   Ehf     = (u16*)(ws + 294976);
    float* esum    = (float*)(ws + 294976);            // aliases Ehf (2 MB span)
    int*   toklist = (int*)out2;                       // out2 region as scratch

    hipMemsetAsync(refCnt, 0, sizeof(int), stream);
    hipMemsetAsync(counts, 0, KCB * sizeof(int), stream);

    eprep_kernel<<<KCB / 4, 256, 0, stream>>>(E, esq, Ehf);
    score_kernel<<<NTOK / 128, 512, 0, stream>>>(z, Ehf, esq, idx_ws, out1, refCnt, refList, counts);
    // Ehf dead from here; zero esum over that region (stream-ordered)
    hipMemsetAsync(esum, 0, (size_t)KCB * DIM * sizeof(float), stream);
    refine_kernel<<<1024, 256, 0, stream>>>(z, E, refCnt, refList, idx_ws, out1, counts);
    scan_kernel<<<1, 1024, 0, stream>>>(counts, cursor, base, cs, out3, n_ws);
    scatter_kernel<<<NTOK / 1024, 256, 0, stream>>>(idx_ws, cursor, toklist);
    seg_sum_kernel<<<NTOK / 64, 128, 0, stream>>>(z, E, toklist, idx_ws, out0, esum);
    out24_kernel<<<(KCB * DIM) / 256, 256, 0, stream>>>(ea, esum, out3, n_ws, out2, out4);
}

// Round 18
// 370.461 us; speedup vs baseline: 1.0927x; 1.0927x over previous
//
#include <hip/hip_runtime.h>
#include <cfloat>

#define NTOK 65536
#define DIM  512
#define KCB  1024
#define TAU  0.12f
#define REF_CAP 4096

typedef unsigned short u16;
typedef __attribute__((ext_vector_type(8))) _Float16 half8;
typedef __attribute__((ext_vector_type(4))) float f32x4;

#define AS1(p) ((const __attribute__((address_space(1))) void*)(p))
#define AS3(p) ((__attribute__((address_space(3))) void*)(p))

// ---------------- ws layout (bytes) ----------------
// 0       : idx       int[NTOK]        262144
// 262144  : esq       f32[KCB]         4096    -> 266240
// 266240  : refCount  int (16B pad)            -> 266256
// 266256  : refList   int[REF_CAP]     16384   -> 282640
// 282640  : n         f32                      -> 282656 (pad)
// 282656  : counts    int[KCB]         4096    -> 286752
// 286752  : cursor    int[KCB]         4096    -> 290848
// 290848  : base      int[KCB]         4096    -> 294944
// 294976  : E_hf      f16[KCB*DIM]     1048576 -> 1343552
// esum f32[KCB*DIM] (2 MB) aliases E_hf.. (dead after score), end 2392128
// toklist int[NTOK] lives in d_out's out2 region (dead until out24_kernel)

__device__ __forceinline__ u16 h2u(_Float16 h) {
    u16 u; __builtin_memcpy(&u, &h, 2); return u;
}

// Fused E prep: wave per code row -> esq (shuffle reduce) + packed f16 Ehf
__global__ __launch_bounds__(256) void eprep_kernel(const float* __restrict__ E,
                                                    float* __restrict__ esq,
                                                    u16* __restrict__ Ehf)
{
    const int lane = threadIdx.x & 63;
    const int wv   = threadIdx.x >> 6;
    const int k    = blockIdx.x * 4 + wv;
    const float* er = E + (size_t)k * DIM + lane * 8;
    const float4 a = *(const float4*)er;
    const float4 b = *(const float4*)(er + 4);
    float s = a.x*a.x + a.y*a.y + a.z*a.z + a.w*a.w
            + b.x*b.x + b.y*b.y + b.z*b.z + b.w*b.w;
    const float v[8] = {a.x, a.y, a.z, a.w, b.x, b.y, b.z, b.w};
    unsigned int* ep = (unsigned int*)Ehf + (size_t)k * 256 + lane * 4;
    #pragma unroll
    for (int j = 0; j < 4; ++j) {
        const _Float16 h0 = (_Float16)v[2*j], h1 = (_Float16)v[2*j+1];
        ep[j] = ((unsigned int)h2u(h1) << 16) | h2u(h0);
    }
    for (int off = 32; off > 0; off >>= 1) s += __shfl_down(s, off, 64);
    if (lane == 0) esq[k] = s;
}

// Convert one f32 to f16 hi + f16 residual, all-static indices (rule #20)
#define CVT(ZH, ZL, J, VAL) { const _Float16 hv_ = (_Float16)(VAL); \
    (ZH)[J] = hv_; (ZL)[J] = (_Float16)((VAL) - (float)hv_); }

#define LOADK(KC, ZH, ZL) { \
    const float4 a_ = *(const float4*)(zr + (KC) * 32); \
    const float4 b_ = *(const float4*)(zr + (KC) * 32 + 4); \
    CVT(ZH, ZL, 0, a_.x) CVT(ZH, ZL, 1, a_.y) \
    CVT(ZH, ZL, 2, a_.z) CVT(ZH, ZL, 3, a_.w) \
    CVT(ZH, ZL, 4, b_.x) CVT(ZH, ZL, 5, b_.y) \
    CVT(ZH, ZL, 6, b_.z) CVT(ZH, ZL, 7, b_.w) }

// Loop-invariant per-lane LDS read offsets (elements) within a 16-row half
#define DSOFF(KC) const int off##KC = lo16 * 512 + \
    (((((KC) << 2) | hi16) ^ lo16) << 3);

// B-frag read: precomputed offset + compile-time half offset (HOFF folds
// into the ds_read offset immediate) -> zero per-chunk addr VALU
#define KSTEP(KC, ZH, ZL, HOFF) { \
    const half8 eh_ = *(const half8*)&ehi_t[off##KC + (HOFF)]; \
    accA = __builtin_amdgcn_mfma_f32_16x16x32_f16((ZH), eh_, accA, 0, 0, 0); \
    accB = __builtin_amdgcn_mfma_f32_16x16x32_f16((ZL), eh_, accB, 0, 0, 0); }

// stage 32-code tile: 8 waves x 4 rows, named induction pointers
#define STAGE { \
    __builtin_amdgcn_global_load_lds(AS1(gp0), AS3(&ehi_t[c0 * 512]), 16, 0, 0); \
    __builtin_amdgcn_global_load_lds(AS1(gp1), AS3(&ehi_t[c1 * 512]), 16, 0, 0); \
    __builtin_amdgcn_global_load_lds(AS1(gp2), AS3(&ehi_t[c2 * 512]), 16, 0, 0); \
    __builtin_amdgcn_global_load_lds(AS1(gp3), AS3(&ehi_t[c3 * 512]), 16, 0, 0); \
    gp0 += 16384; gp1 += 16384; gp2 += 16384; gp3 += 16384; }

// one 16-code half: 16 ds_read + 32 MFMA + top-2 update
#define COMPUTE(HOFF, CODE0) { \
    const int code_ = (CODE0) + lo16; \
    const float ej = esq_lds[code_]; \
    f32x4 accA = {0.f, 0.f, 0.f, 0.f}; \
    f32x4 accB = {0.f, 0.f, 0.f, 0.f}; \
    KSTEP(0,  zh0,  zl0,  HOFF) KSTEP(1,  zh1,  zl1,  HOFF) \
    KSTEP(2,  zh2,  zl2,  HOFF) KSTEP(3,  zh3,  zl3,  HOFF) \
    KSTEP(4,  zh4,  zl4,  HOFF) KSTEP(5,  zh5,  zl5,  HOFF) \
    KSTEP(6,  zh6,  zl6,  HOFF) KSTEP(7,  zh7,  zl7,  HOFF) \
    KSTEP(8,  zh8,  zl8,  HOFF) KSTEP(9,  zh9,  zl9,  HOFF) \
    KSTEP(10, zh10, zl10, HOFF) KSTEP(11, zh11, zl11, HOFF) \
    KSTEP(12, zh12, zl12, HOFF) KSTEP(13, zh13, zl13, HOFF) \
    KSTEP(14, zh14, zl14, HOFF) KSTEP(15, zh15, zl15, HOFF) \
    _Pragma("unroll") \
    for (int r = 0; r < 4; ++r) { \
        const float dist = fmaf(-2.0f, accB[r], fmaf(-2.0f, accA[r], ej)); \
        if (dist < d1[r]) { d2[r] = d1[r]; d1[r] = dist; i1[r] = code_; } \
        else              { d2[r] = fminf(d2[r], dist); } \
    } }

// MFMA split-f16 scoring: 128 tokens/block (8 waves x 16 tokens, K=512 in
// named regs); 32 chunks of 32 codes, single-buffer LDS, 2-barrier template.
__global__ __launch_bounds__(512, 2) void score_kernel(
    const float* __restrict__ z,
    const u16* __restrict__ Ehf,
    const float* __restrict__ esq,
    int* __restrict__ idx_ws, float* __restrict__ idx_out,
    int* __restrict__ refCount, int* __restrict__ refList)
{
    __shared__ _Float16 ehi_t[32 * 512];   // 32 KB, granule-swizzled rows
    __shared__ float esq_lds[KCB];         // 4 KB

    const int tid  = threadIdx.x;
    const int lane = tid & 63;
    const int wv   = tid >> 6;             // 0..7
    const int lo16 = lane & 15;
    const int hi16 = lane >> 4;
    const int blk  = blockIdx.x;
    const int tokbase = blk * 128 + wv * 16;

    for (int i = tid; i < KCB; i += 512) esq_lds[i] = esq[i];

    // A fragments: 16 tokens x K=512, f16 hi/lo, NAMED registers.
    // A[row][k]: row = lo16, k = kc*32 + hi16*8 + j
    const float* zr = z + (size_t)(tokbase + lo16) * DIM + (hi16 << 3);
    half8 zh0,zh1,zh2,zh3,zh4,zh5,zh6,zh7,zh8,zh9,zh10,zh11,zh12,zh13,zh14,zh15;
    half8 zl0,zl1,zl2,zl3,zl4,zl5,zl6,zl7,zl8,zl9,zl10,zl11,zl12,zl13,zl14,zl15;
    LOADK(0,  zh0,  zl0)  LOADK(1,  zh1,  zl1)  LOADK(2,  zh2,  zl2)
    LOADK(3,  zh3,  zl3)  LOADK(4,  zh4,  zl4)  LOADK(5,  zh5,  zl5)
    LOADK(6,  zh6,  zl6)  LOADK(7,  zh7,  zl7)  LOADK(8,  zh8,  zl8)
    LOADK(9,  zh9,  zl9)  LOADK(10, zh10, zl10) LOADK(11, zh11, zl11)
    LOADK(12, zh12, zl12) LOADK(13, zh13, zl13) LOADK(14, zh14, zl14)
    LOADK(15, zh15, zl15)

    // precomputed LDS read offsets (loop-invariant)
    DSOFF(0)  DSOFF(1)  DSOFF(2)  DSOFF(3)
    DSOFF(4)  DSOFF(5)  DSOFF(6)  DSOFF(7)
    DSOFF(8)  DSOFF(9)  DSOFF(10) DSOFF(11)
    DSOFF(12) DSOFF(13) DSOFF(14) DSOFF(15)

    // staging induction pointers: wave wv stages tile rows wv*4..wv*4+3;
    // per-lane pre-swizzled source so swizzled reads are conflict-free
    const int c0 = (wv << 2), c1 = c0 + 1, c2 = c0 + 2, c3 = c0 + 3;
    const u16* gp0 = Ehf + (size_t)c0 * 512 + ((lane ^ (c0 & 15)) << 3);
    const u16* gp1 = Ehf + (size_t)c1 * 512 + ((lane ^ (c1 & 15)) << 3);
    const u16* gp2 = Ehf + (size_t)c2 * 512 + ((lane ^ (c2 & 15)) << 3);
    const u16* gp3 = Ehf + (size_t)c3 * 512 + ((lane ^ (c3 & 15)) << 3);

    float d1[4], d2[4]; int i1[4];
    #pragma unroll
    for (int r = 0; r < 4; ++r) { d1[r] = FLT_MAX; d2[r] = FLT_MAX; i1[r] = KCB; }

    for (int ch = 0; ch < 32; ++ch) {
        __syncthreads();   // previous chunk's reads done before overwrite
        STAGE
        __syncthreads();   // drains vmcnt: tile ready (compiler-managed)
        COMPUTE(0,    (ch << 5))        // codes [ch*32,      ch*32 + 16)
        COMPUTE(8192, (ch << 5) + 16)   // codes [ch*32 + 16, ch*32 + 32)
    }

    // merge top-2 across the 16 code-lanes (low 4 lane bits)
    #pragma unroll
    for (int off = 1; off < 16; off <<= 1) {
        #pragma unroll
        for (int r = 0; r < 4; ++r) {
            const float od1 = __shfl_xor(d1[r], off, 64);
            const int   oi1 = __shfl_xor(i1[r], off, 64);
            const float od2 = __shfl_xor(d2[r], off, 64);
            float loser;
            if (od1 < d1[r] || (od1 == d1[r] && oi1 < i1[r])) {
                loser = d1[r]; d1[r] = od1; i1[r] = oi1;
            } else {
                loser = od1;
            }
            d2[r] = fminf(fminf(d2[r], od2), loser);
        }
    }
    if (lo16 == 0) {
        #pragma unroll
        for (int r = 0; r < 4; ++r) {
            const int token = tokbase + (hi16 << 2) + r;
            idx_ws[token]  = i1[r];
            idx_out[token] = (float)i1[r];
            if (d2[r] - d1[r] < TAU) {
                int slot = atomicAdd(refCount, 1);
                if (slot < REF_CAP) refList[slot] = token;
            }
        }
    }
}

// f64 exact re-scoring of near-tie tokens. 16 groups of 16 lanes per block;
// group owns a code (lane = 32 dims), 2 codes in flight, 4-level reduce.
__global__ __launch_bounds__(256) void refine_kernel(
    const float* __restrict__ z, const float* __restrict__ E,
    const int* __restrict__ refCount, const int* __restrict__ refList,
    int* __restrict__ idx_ws, float* __restrict__ idx_out)
{
    __shared__ double dists[KCB];
    const int tid = threadIdx.x;
    const int grp = tid >> 4;
    const int q   = tid & 15;
    int rc = *refCount; if (rc > REF_CAP) rc = REF_CAP;
    for (int r = blockIdx.x; r < rc; r += gridDim.x) {
        const int token = refList[r];
        double zr[32];
        {
            const float* zp = z + (size_t)token * DIM + q * 32;
            #pragma unroll
            for (int j = 0; j < 8; ++j) {
                const float4 v = *(const float4*)(zp + j * 4);
                zr[j*4+0] = (double)v.x; zr[j*4+1] = (double)v.y;
                zr[j*4+2] = (double)v.z; zr[j*4+3] = (double)v.w;
            }
        }
        for (int c = grp; c < KCB; c += 32) {
            const int c2 = c + 16;
            const float* ep  = E + (size_t)c  * DIM + q * 32;
            const float* ep2 = E + (size_t)c2 * DIM + q * 32;
            double s = 0.0, s2 = 0.0;
            #pragma unroll
            for (int j = 0; j < 8; ++j) {
                const float4 a = *(const float4*)(ep  + j * 4);
                const float4 b = *(const float4*)(ep2 + j * 4);
                double d;
                d = zr[j*4+0] - (double)a.x; s  = fma(d, d, s);
                d = zr[j*4+1] - (double)a.y; s  = fma(d, d, s);
                d = zr[j*4+2] - (double)a.z; s  = fma(d, d, s);
                d = zr[j*4+3] - (double)a.w; s  = fma(d, d, s);
                d = zr[j*4+0] - (double)b.x; s2 = fma(d, d, s2);
                d = zr[j*4+1] - (double)b.y; s2 = fma(d, d, s2);
                d = zr[j*4+2] - (double)b.z; s2 = fma(d, d, s2);
                d = zr[j*4+3] - (double)b.w; s2 = fma(d, d, s2);
            }
            #pragma unroll
            for (int off = 1; off < 16; off <<= 1) {
                s  += __shfl_xor(s,  off, 64);
                s2 += __shfl_xor(s2, off, 64);
            }
            if (q == 0) { dists[c] = s; dists[c2] = s2; }
        }
        __syncthreads();
        if (tid < 64) {
            const int lane = tid;
            double best = dists[lane]; int bi = lane;
            for (int c = lane + 64; c < KCB; c += 64) {
                const double dv = dists[c];
                if (dv < best) { best = dv; bi = c; }   // ascending: keeps lowest idx
            }
            for (int off = 32; off > 0; off >>= 1) {
                const double ob = __shfl_down(best, off, 64);
                const int    oi = __shfl_down(bi, off, 64);
                if (ob < best || (ob == best && oi < bi)) { best = ob; bi = oi; }
            }
            if (lane == 0) { idx_ws[token] = bi; idx_out[token] = (float)bi; }
        }
        __syncthreads();
    }
}

// ---- counting sort of tokens by code ----
__global__ __launch_bounds__(256) void hist_kernel(const int* __restrict__ idx,
                                                   int* __restrict__ counts)
{
    __shared__ int h[KCB];
    const int tid = threadIdx.x;
    for (int i = tid; i < KCB; i += 256) h[i] = 0;
    __syncthreads();
    const int b0 = blockIdx.x * 1024;
    #pragma unroll
    for (int j = 0; j < 4; ++j) atomicAdd(&h[idx[b0 + j * 256 + tid]], 1);
    __syncthreads();
    for (int i = tid; i < KCB; i += 256) {
        const int v = h[i];
        if (v) atomicAdd(&counts[i], v);
    }
}

__global__ __launch_bounds__(1024) void scan_kernel(const int* __restrict__ counts,
                                                    int* __restrict__ cursor,
                                                    int* __restrict__ base)
{
    const int tid = threadIdx.x, lane = tid & 63, wv = tid >> 6;
    const int v = counts[tid];
    int s = v;
    #pragma unroll
    for (int off = 1; off < 64; off <<= 1) {
        const int nb = __shfl_up(s, off, 64);
        if (lane >= off) s += nb;
    }
    __shared__ int wsum[16], wbase[16];
    if (lane == 63) wsum[wv] = s;
    __syncthreads();
    if (tid == 0) {
        int r = 0;
        for (int w = 0; w < 16; ++w) { wbase[w] = r; r += wsum[w]; }
    }
    __syncthreads();
    const int excl = wbase[wv] + s - v;
    cursor[tid] = excl;
    base[tid]   = excl;
}

__global__ __launch_bounds__(256) void scatter_kernel(const int* __restrict__ idx,
                                                      int* __restrict__ cursor,
                                                      int* __restrict__ toklist)
{
    const int b0 = blockIdx.x * 1024;
    #pragma unroll
    for (int j = 0; j < 4; ++j) {
        const int t = b0 + j * 256 + threadIdx.x;
        const int k = idx[t];
        const int slot = atomicAdd(&cursor[k], 1);
        toklist[slot] = t;
    }
}

// Uniform-work segment sum: block b owns sorted slots [b*64, b*64+64).
// R14-best form: 256 threads x float2, 1-deep row prefetch.
__global__ __launch_bounds__(256) void seg_sum_kernel(
    const float* __restrict__ z, const float* __restrict__ E,
    const int* __restrict__ toklist, const int* __restrict__ idx,
    float* __restrict__ out0, float* __restrict__ esum)
{
    __shared__ int toks[64];
    __shared__ int ks[64];
    const int tid  = threadIdx.x;
    const int seg0 = blockIdx.x * 64;
    if (tid < 64) toks[tid] = toklist[seg0 + tid];
    __syncthreads();
    if (tid < 64) ks[tid] = idx[toks[tid]];
    __syncthreads();

    const int d = tid * 2;
    int curk = ks[0];
    float2 er  = *(const float2*)(E + (size_t)curk * DIM + d);
    float2 acc = {0.f, 0.f};
    float2 v   = *(const float2*)(z + (size_t)toks[0] * DIM + d);
    for (int i = 0; i < 64; ++i) {
        const int t = toks[i];
        float2 vn;
        if (i < 63) vn = *(const float2*)(z + (size_t)toks[i + 1] * DIM + d);
        const int k = ks[i];
        if (k != curk) {                       // block-uniform branch (~2/segment)
            atomicAdd(&esum[(size_t)curk * DIM + d],     acc.x);
            atomicAdd(&esum[(size_t)curk * DIM + d + 1], acc.y);
            acc.x = 0.f; acc.y = 0.f;
            curk = k;
            er = *(const float2*)(E + (size_t)k * DIM + d);
        }
        *(float2*)(out0 + (size_t)t * DIM + d) = er;
        acc.x += v.x; acc.y += v.y;
        v = vn;
    }
    atomicAdd(&esum[(size_t)curk * DIM + d],     acc.x);
    atomicAdd(&esum[(size_t)curk * DIM + d + 1], acc.y);
}

__global__ __launch_bounds__(1024) void cs_n_kernel(const float* __restrict__ cs,
    const int* __restrict__ counts, float* __restrict__ out3,
    float* __restrict__ n_ws)
{
    const int k = threadIdx.x;
    const float ncs = 0.99f * cs[k] + 0.01f * (float)counts[k];
    out3[k] = ncs;
    float s = ncs;
    for (int off = 32; off > 0; off >>= 1) s += __shfl_down(s, off, 64);
    __shared__ float red[16];
    const int lane = k & 63, wv = k >> 6;
    if (lane == 0) red[wv] = s;
    __syncthreads();
    if (k == 0) {
        float t = 0.f;
        for (int i = 0; i < 16; ++i) t += red[i];
        n_ws[0] = t;
    }
}

__global__ __launch_bounds__(256) void out24_kernel(const float* __restrict__ ea,
    const float* __restrict__ esum, const float* __restrict__ out3,
    const float* __restrict__ n_ws, float* __restrict__ out2,
    float* __restrict__ out4)
{
    const size_t i = (size_t)blockIdx.x * 256 + threadIdx.x;
    const int k = (int)(i >> 9);
    const float n = n_ws[0];
    const float smoothed = (out3[k] + 1e-5f) / (n + 0.01024f) * n;
    const float nea = 0.99f * ea[i] + 0.01f * esum[i];
    out4[i] = nea;
    out2[i] = nea / smoothed;
}

extern "C" void kernel_launch(void* const* d_in, const int* in_sizes, int n_in,
                              void* d_out, int out_size, void* d_ws, size_t ws_size,
                              hipStream_t stream)
{
    const float* z  = (const float*)d_in[0];
    const float* E  = (const float*)d_in[1];
    const float* cs = (const float*)d_in[2];
    const float* ea = (const float*)d_in[3];

    float* out0 = (float*)d_out;                       // quantized_st [NTOK*DIM]
    float* out1 = out0 + (size_t)NTOK * DIM;           // indices (as f32) [NTOK]
    float* out2 = out1 + NTOK;                         // new_embedding [KCB*DIM]
    float* out3 = out2 + (size_t)KCB * DIM;            // new_cluster_size [KCB]
    float* out4 = out3 + KCB;                          // new_embed_avg [KCB*DIM]

    char* ws = (char*)d_ws;
    int*   idx_ws  = (int*)ws;
    float* esq     = (float*)(ws + 262144);
    int*   refCnt  = (int*)(ws + 266240);
    int*   refList = (int*)(ws + 266256);
    float* n_ws    = (float*)(ws + 282640);
    int*   counts  = (int*)(ws + 282656);
    int*   cursor  = (int*)(ws + 286752);
    int*   base    = (int*)(ws + 290848);
    u16*   Ehf     = (u16*)(ws + 294976);
    float* esum    = (float*)(ws + 294976);            // aliases Ehf (2 MB span)
    int*   toklist = (int*)out2;                       // out2 region as scratch

    hipMemsetAsync(refCnt, 0, sizeof(int), stream);
    hipMemsetAsync(counts, 0, KCB * sizeof(int), stream);

    eprep_kernel<<<KCB / 4, 256, 0, stream>>>(E, esq, Ehf);
    score_kernel<<<NTOK / 128, 512, 0, stream>>>(z, Ehf, esq, idx_ws, out1, refCnt, refList);
    // Ehf dead from here; zero esum over that region (stream-ordered)
    hipMemsetAsync(esum, 0, (size_t)KCB * DIM * sizeof(float), stream);
    refine_kernel<<<1024, 256, 0, stream>>>(z, E, refCnt, refList, idx_ws, out1);
    hist_kernel<<<NTOK / 1024, 256, 0, stream>>>(idx_ws, counts);
    scan_kernel<<<1, 1024, 0, stream>>>(counts, cursor, base);
    scatter_kernel<<<NTOK / 1024, 256, 0, stream>>>(idx_ws, cursor, toklist);
    seg_sum_kernel<<<NTOK / 64, 256, 0, stream>>>(z, E, toklist, idx_ws, out0, esum);
    cs_n_kernel<<<1, 1024, 0, stream>>>(cs, counts, out3, n_ws);
    out24_kernel<<<(KCB * DIM) / 256, 256, 0, stream>>>(ea, esum, out3, n_ws, out2, out4);
}